// Round 3
// baseline (43.623 us; speedup 1.0000x reference)
//
#include <hip/hip_runtime.h>
#include <math.h>

// SVD rigid registration, two kernels:
//  K1: per-half-batch weighted moments (W, St[3], Ss[3], M[9]) — one 64-lane
//      wave per half-batch (SPLIT=2), 16 pts/lane, folding multi-value wave
//      reduction (17 shuffles instead of 96), partials -> d_ws.
//  K2: one thread per batch: sum SPLIT partials, cov assembly (double) +
//      det-scaled Newton polar iteration (R = U@Vh), writes the 4x4 T.

constexpr int BN = 2048;  // points per batch

template <int SPLIT>
__global__ __launch_bounds__(256) void moments_kernel(
    const float* __restrict__ target,
    const float* __restrict__ source,
    const float* __restrict__ weights,
    float* __restrict__ ws)
{
    const int lane = threadIdx.x & 63;
    const int wid  = blockIdx.x * 4 + (threadIdx.x >> 6);  // global wave id
    const int b    = wid / SPLIT;
    const int part = wid % SPLIT;

    constexpr int GROUPS = BN / 4;                 // 4-point groups per batch
    constexpr int ITERS  = GROUPS / (SPLIT * 64);  // groups per lane

    const float4* t4 = reinterpret_cast<const float4*>(target + (size_t)b * BN * 3);
    const float4* s4 = reinterpret_cast<const float4*>(source + (size_t)b * BN * 3);
    const float4* w4 = reinterpret_cast<const float4*>(weights + (size_t)b * BN);
    const int pg0 = part * (GROUPS / SPLIT);

    // [0]=W, [1..3]=sum w*t, [4..6]=sum w*s, [7..15]=M[i][j]=sum w*t_i*s_j
    float acc[16];
#pragma unroll
    for (int i = 0; i < 16; ++i) acc[i] = 0.f;

#pragma unroll
    for (int it = 0; it < ITERS; ++it) {
        const int g = pg0 + it * 64 + lane;        // 4-point group index
        float4 t0 = t4[g * 3 + 0], t1 = t4[g * 3 + 1], t2 = t4[g * 3 + 2];
        float4 s0 = s4[g * 3 + 0], s1 = s4[g * 3 + 1], s2 = s4[g * 3 + 2];
        float4 wv = w4[g];

        float tx[4] = {t0.x, t0.w, t1.z, t2.y};
        float ty[4] = {t0.y, t1.x, t1.w, t2.z};
        float tz[4] = {t0.z, t1.y, t2.x, t2.w};
        float sx[4] = {s0.x, s0.w, s1.z, s2.y};
        float sy[4] = {s0.y, s1.x, s1.w, s2.z};
        float sz[4] = {s0.z, s1.y, s2.x, s2.w};
        float ww[4] = {wv.x, wv.y, wv.z, wv.w};

#pragma unroll
        for (int j = 0; j < 4; ++j) {
            float w = ww[j];
            acc[0] += w;
            float wtx = w * tx[j], wty = w * ty[j], wtz = w * tz[j];
            acc[1] += wtx;  acc[2] += wty;  acc[3] += wtz;
            acc[4] += w * sx[j]; acc[5] += w * sy[j]; acc[6] += w * sz[j];
            acc[7]  += wtx * sx[j]; acc[8]  += wtx * sy[j]; acc[9]  += wtx * sz[j];
            acc[10] += wty * sx[j]; acc[11] += wty * sy[j]; acc[12] += wty * sz[j];
            acc[13] += wtz * sx[j]; acc[14] += wtz * sy[j]; acc[15] += wtz * sz[j];
        }
    }

    // Folding multi-value reduction: at each round, each lane keeps half its
    // values and ships the other half to its XOR partner. Value count:
    // 16 -> 8 -> 4 -> 2 -> 1, then 2 plain butterfly steps. All indices static.
    {
        // round 1: off=32, 16 -> 8
        const bool u5 = (lane & 32) != 0;
#pragma unroll
        for (int v = 0; v < 8; ++v) {
            float send = u5 ? acc[v] : acc[v + 8];
            float r = __shfl_xor(send, 32);
            acc[v] = (u5 ? acc[v + 8] : acc[v]) + r;
        }
        // round 2: off=16, 8 -> 4
        const bool u4 = (lane & 16) != 0;
#pragma unroll
        for (int v = 0; v < 4; ++v) {
            float send = u4 ? acc[v] : acc[v + 4];
            float r = __shfl_xor(send, 16);
            acc[v] = (u4 ? acc[v + 4] : acc[v]) + r;
        }
        // round 3: off=8, 4 -> 2
        const bool u3 = (lane & 8) != 0;
#pragma unroll
        for (int v = 0; v < 2; ++v) {
            float send = u3 ? acc[v] : acc[v + 2];
            float r = __shfl_xor(send, 8);
            acc[v] = (u3 ? acc[v + 2] : acc[v]) + r;
        }
        // round 4: off=4, 2 -> 1
        const bool u2 = (lane & 4) != 0;
        {
            float send = u2 ? acc[0] : acc[1];
            float r = __shfl_xor(send, 4);
            acc[0] = (u2 ? acc[1] : acc[0]) + r;
        }
        // final butterfly over the 4 lanes sharing this accumulator
        acc[0] += __shfl_xor(acc[0], 2);
        acc[0] += __shfl_xor(acc[0], 1);
    }

    // lane -> accumulator index (from the keep/send pattern above)
    const int aidx = (((lane >> 5) & 1) << 3) | (((lane >> 4) & 1) << 2) |
                     (((lane >> 3) & 1) << 1) | ((lane >> 2) & 1);
    if ((lane & 3) == 0)
        ws[((size_t)b * SPLIT + part) * 16 + aidx] = acc[0];
}

template <int SPLIT>
__global__ __launch_bounds__(256) void polar_kernel(
    const float* __restrict__ ws,
    float* __restrict__ out,
    int B)
{
    const int b = blockIdx.x * 256 + threadIdx.x;
    if (b >= B) return;

    double v[16];
#pragma unroll
    for (int i = 0; i < 16; ++i) v[i] = 0.0;
#pragma unroll
    for (int p = 0; p < SPLIT; ++p) {
        const float4* i4 = reinterpret_cast<const float4*>(ws + ((size_t)b * SPLIT + p) * 16);
        float4 p0 = i4[0], p1 = i4[1], p2 = i4[2], p3 = i4[3];
        float f[16] = {p0.x, p0.y, p0.z, p0.w,  p1.x, p1.y, p1.z, p1.w,
                       p2.x, p2.y, p2.z, p2.w,  p3.x, p3.y, p3.z, p3.w};
#pragma unroll
        for (int i = 0; i < 16; ++i) v[i] += (double)f[i];
    }

    const double W  = v[0];
    const double Wd = W + 1e-8;
    double St[3] = {v[1], v[2], v[3]};
    double Ss[3] = {v[4], v[5], v[6]};
    double mt[3], ms[3];
#pragma unroll
    for (int i = 0; i < 3; ++i) { mt[i] = St[i] / Wd; ms[i] = Ss[i] / Wd; }

    double A[3][3];
#pragma unroll
    for (int i = 0; i < 3; ++i)
#pragma unroll
        for (int j = 0; j < 3; ++j)
            A[i][j] = v[7 + i * 3 + j] - mt[i] * Ss[j] - ms[j] * St[i] + mt[i] * ms[j] * W;

    // Newton polar iteration with determinant scaling:
    //   X <- 0.5 * (mu*X + (1/(mu*det)) * cof(X))  ->  orthogonal polar factor U@Vh
    double X[3][3];
#pragma unroll
    for (int i = 0; i < 3; ++i)
#pragma unroll
        for (int j = 0; j < 3; ++j) X[i][j] = A[i][j];

#pragma unroll
    for (int iter = 0; iter < 12; ++iter) {
        double C[3][3];
        C[0][0] = X[1][1]*X[2][2] - X[1][2]*X[2][1];
        C[0][1] = X[1][2]*X[2][0] - X[1][0]*X[2][2];
        C[0][2] = X[1][0]*X[2][1] - X[1][1]*X[2][0];
        C[1][0] = X[0][2]*X[2][1] - X[0][1]*X[2][2];
        C[1][1] = X[0][0]*X[2][2] - X[0][2]*X[2][0];
        C[1][2] = X[0][1]*X[2][0] - X[0][0]*X[2][1];
        C[2][0] = X[0][1]*X[1][2] - X[0][2]*X[1][1];
        C[2][1] = X[0][2]*X[1][0] - X[0][0]*X[1][2];
        C[2][2] = X[0][0]*X[1][1] - X[0][1]*X[1][0];
        double det = X[0][0]*C[0][0] + X[0][1]*C[0][1] + X[0][2]*C[0][2];
        double ad  = fabs(det);
        if (!(ad > 1e-300)) { det = (det >= 0.0) ? 1e-300 : -1e-300; ad = 1e-300; }

        double mu = 1.0;
        if (iter < 9) {
            float adf = (float)ad;
            if (adf > 0.f && isfinite(adf))
                mu = (double)exp2f(-log2f(adf) * (1.0f / 3.0f));
        }
        double k1 = 0.5 * mu;
        double k2 = 0.5 / (mu * det);
#pragma unroll
        for (int i = 0; i < 3; ++i)
#pragma unroll
            for (int j = 0; j < 3; ++j)
                X[i][j] = k1 * X[i][j] + k2 * C[i][j];
    }

    double tvec[3];
#pragma unroll
    for (int i = 0; i < 3; ++i) {
        double s = mt[i];
#pragma unroll
        for (int k = 0; k < 3; ++k) s -= X[i][k] * ms[k];
        tvec[i] = s;
    }

    float4* o = reinterpret_cast<float4*>(out + (size_t)b * 16);
    o[0] = make_float4((float)X[0][0], (float)X[0][1], (float)X[0][2], (float)tvec[0]);
    o[1] = make_float4((float)X[1][0], (float)X[1][1], (float)X[1][2], (float)tvec[1]);
    o[2] = make_float4((float)X[2][0], (float)X[2][1], (float)X[2][2], (float)tvec[2]);
    o[3] = make_float4(0.f, 0.f, 0.f, 1.f);
}

extern "C" void kernel_launch(void* const* d_in, const int* in_sizes, int n_in,
                              void* d_out, int out_size, void* d_ws, size_t ws_size,
                              hipStream_t stream) {
    const float* target  = (const float*)d_in[0];
    const float* source  = (const float*)d_in[1];
    const float* weights = (const float*)d_in[2];
    float* out = (float*)d_out;
    float* ws  = (float*)d_ws;

    const int B = in_sizes[2] / BN;  // weights flat = B*N

    if (ws_size >= (size_t)B * 2 * 16 * sizeof(float)) {
        // SPLIT=2: 2 waves per batch
        moments_kernel<2><<<B * 2 / 4, 256, 0, stream>>>(target, source, weights, ws);
        polar_kernel<2><<<(B + 255) / 256, 256, 0, stream>>>(ws, out, B);
    } else {
        moments_kernel<1><<<B / 4, 256, 0, stream>>>(target, source, weights, ws);
        polar_kernel<1><<<(B + 255) / 256, 256, 0, stream>>>(ws, out, B);
    }
}